// Round 1
// baseline (251.481 us; speedup 1.0000x reference)
//
#include <hip/hip_runtime.h>

#define BS     8192
#define DIM    768
#define NPART  32               // BS / BN column partitions
#define BM     256
#define BN     256
#define BK     64
#define NKT    (DIM / BK)       // 12 k-tiles
#define L1B    128              // loss stage-1 blocks
#define L1R    (BS / L1B)       // rows per stage-1 block (64)

typedef __bf16 bfrag_t __attribute__((ext_vector_type(8)));
typedef float  facc_t  __attribute__((ext_vector_type(4)));

typedef const __attribute__((address_space(1))) void gv_t;
typedef __attribute__((address_space(3))) void lv_t;

__device__ __forceinline__ void gll16(const void* g, void* l) {
  // async global->LDS DMA, 16B/lane; LDS dest = wave-uniform base + lane*16
  __builtin_amdgcn_global_load_lds((gv_t*)g, (lv_t*)l, 16, 0, 0);
}

__device__ __forceinline__ unsigned short f2bf(float f) {
  union { float f; unsigned u; } v; v.f = f;
  unsigned u = v.u;
  return (unsigned short)((u + 0x7FFFu + ((u >> 16) & 1u)) >> 16);  // RNE
}

// ---------------- fused: fp32 copy-out (both), bf16 convert (both), diag ----------------
__global__ void prep_kernel(const float* __restrict__ nl, const float* __restrict__ cd,
                            float* __restrict__ cd_copy, float* __restrict__ nl_copy,
                            unsigned short* __restrict__ nlb, unsigned short* __restrict__ cdb,
                            float* __restrict__ dg) {
  const int lane = threadIdx.x & 63;
  const int wave = threadIdx.x >> 6;
  const int row  = blockIdx.x * 4 + wave;
  const size_t rbase = (size_t)row * DIM;
  const float4* ar = reinterpret_cast<const float4*>(nl + rbase);
  const float4* br = reinterpret_cast<const float4*>(cd + rbase);
  float4* wa = reinterpret_cast<float4*>(nl_copy + rbase);
  float4* wb = reinterpret_cast<float4*>(cd_copy + rbase);
  ushort4* ba = reinterpret_cast<ushort4*>(nlb + rbase);
  ushort4* bb = reinterpret_cast<ushort4*>(cdb + rbase);

  float s = 0.f;
#pragma unroll
  for (int i = 0; i < 3; ++i) {                 // 192 float4 per row, 3 per lane
    int idx = lane + 64 * i;
    float4 x = ar[idx];
    float4 y = br[idx];
    wa[idx] = x;
    wb[idx] = y;
    ushort4 xb, yb;
    xb.x = f2bf(x.x); xb.y = f2bf(x.y); xb.z = f2bf(x.z); xb.w = f2bf(x.w);
    yb.x = f2bf(y.x); yb.y = f2bf(y.y); yb.z = f2bf(y.z); yb.w = f2bf(y.w);
    ba[idx] = xb;
    bb[idx] = yb;
    s += x.x * y.x + x.y * y.y + x.z * y.z + x.w * y.w;
  }
#pragma unroll
  for (int off = 32; off; off >>= 1) s += __shfl_xor(s, off, 64);
  if (lane == 0) dg[row] = s;
}

// ---------------- 256x256 8-phase pipelined GEMM (bf16 MFMA) + lse partials ----------------
// block: 512 threads (8 waves as 2M x 4N, each owning 128x64 of C), tile 256x256, BK=64.
// grid: (NPART, BS/BM) = (32, 32) = 1024 blocks. LDS: 128 KiB (A,B double-buffered).
// Schedule (steady state, iteration t computes K-tiles 2t (buf0) and 2t+1 (buf1)):
//   ph1: ds[B(2t) all + A(2t) mt0,1] | issue A0,A1(2t+1)   -> MFMA q0
//   ph2: ds[A mt2,3]                 | issue B0(2t+2)       -> q1
//   ph3: ds[A mt4,5]                 | issue B1(2t+2)       -> q2
//   ph4: ds[A mt6,7]                 |                      -> q3, vmcnt(4)
//   ph5: ds[B(2t+1) all + A mt0,1]   | issue A0(2t+2)       -> q0
//   ph6: ds[A mt2,3]                 | issue A1(2t+2)       -> q1
//   ph7: ds[A mt4,5]                 | issue B0(2t+3)       -> q2
//   ph8: ds[A mt6,7]                 | issue B1(2t+3)       -> q3, vmcnt(4)
// Slot safety: B(k) fully read at its first phase; A(k) last read at its 4th phase;
// every prefetch targets a slot whose last reader phase has already closed (barrier).
// vmcnt(4): 4 loads (= next B half-tiles) stay in flight across every barrier.
__global__ __launch_bounds__(512, 2) void gemm_lse_kernel(
    const unsigned short* __restrict__ Abf,
    const unsigned short* __restrict__ Bbf,
    float* __restrict__ pm, float* __restrict__ pl) {
  __shared__ __align__(16) unsigned short As[2 * BM * BK];   // 64 KB
  __shared__ __align__(16) unsigned short Bs[2 * BN * BK];   // 64 KB

  const int tid  = threadIdx.x;
  const int lane = tid & 63;
  const int wave = tid >> 6;
  const int wm   = wave >> 2;      // 0..1  M half
  const int wn   = wave & 3;       // 0..3  N quarter
  const int l15  = lane & 15;
  const int l4   = lane >> 4;
  const int swz  = l15 & 7;
  const int cb   = blockIdx.x;
  const int rb   = blockIdx.y;

  // fragment-read swizzled k8 offsets (shorts) for ks=0,1
  const int k8x0 = ((0 * 4 + l4) ^ swz) * 8;
  const int k8x1 = ((1 * 4 + l4) ^ swz) * 8;

  // staging: unit u (16B) of a tile holds global (row=u>>3, c8=(u&7)^(row&7))
  size_t aoff[4], boff[4];
  int ldso[4];
#pragma unroll
  for (int p = 0; p < 4; ++p) {
    int u   = p * 512 + tid;
    int row = u >> 3;
    int c8  = (u & 7) ^ (row & 7);
    aoff[p] = (size_t)(rb * BM + row) * DIM + c8 * 8;
    boff[p] = (size_t)(cb * BN + row) * DIM + c8 * 8;
    ldso[p] = u * 8;               // shorts within one buf
  }

#define STG_A(kt, h) do { \
    gll16(Abf + aoff[2*(h)]   + (size_t)(kt) * BK, &As[(((kt) & 1) << 14) + ldso[2*(h)]]); \
    gll16(Abf + aoff[2*(h)+1] + (size_t)(kt) * BK, &As[(((kt) & 1) << 14) + ldso[2*(h)+1]]); \
  } while (0)
#define STG_B(kt, h) do { \
    gll16(Bbf + boff[2*(h)]   + (size_t)(kt) * BK, &Bs[(((kt) & 1) << 14) + ldso[2*(h)]]); \
    gll16(Bbf + boff[2*(h)+1] + (size_t)(kt) * BK, &Bs[(((kt) & 1) << 14) + ldso[2*(h)+1]]); \
  } while (0)

  bfrag_t af[2][2];   // 2 m-tiles x 2 ks, reloaded each phase
  bfrag_t bf[4][2];   // 4 n-tiles x 2 ks, loaded at ph1/ph5, live across the K-tile
  facc_t  acc[8][4];
#pragma unroll
  for (int mt = 0; mt < 8; ++mt)
#pragma unroll
    for (int nt = 0; nt < 4; ++nt) acc[mt][nt] = (facc_t){0.f, 0.f, 0.f, 0.f};

#define DS_A(b, q) do { \
    _Pragma("unroll") \
    for (int i_ = 0; i_ < 2; ++i_) { \
      const unsigned short* pA_ = &As[(b) * 16384 + (wm * 128 + (2*(q)+i_) * 16 + l15) * 64]; \
      af[i_][0] = *reinterpret_cast<const bfrag_t*>(pA_ + k8x0); \
      af[i_][1] = *reinterpret_cast<const bfrag_t*>(pA_ + k8x1); \
    } } while (0)
#define DS_B(b) do { \
    _Pragma("unroll") \
    for (int n_ = 0; n_ < 4; ++n_) { \
      const unsigned short* pB_ = &Bs[(b) * 16384 + (wn * 64 + n_ * 16 + l15) * 64]; \
      bf[n_][0] = *reinterpret_cast<const bfrag_t*>(pB_ + k8x0); \
      bf[n_][1] = *reinterpret_cast<const bfrag_t*>(pB_ + k8x1); \
    } } while (0)
#define MFMA_Q(q) do { \
    _Pragma("unroll") \
    for (int i_ = 0; i_ < 2; ++i_) \
      _Pragma("unroll") \
      for (int n_ = 0; n_ < 4; ++n_) { \
        acc[2*(q)+i_][n_] = __builtin_amdgcn_mfma_f32_16x16x32_bf16(af[i_][0], bf[n_][0], acc[2*(q)+i_][n_], 0, 0, 0); \
        acc[2*(q)+i_][n_] = __builtin_amdgcn_mfma_f32_16x16x32_bf16(af[i_][1], bf[n_][1], acc[2*(q)+i_][n_], 0, 0, 0); \
      } } while (0)

#define PH_TOP() do { __builtin_amdgcn_s_barrier(); \
    asm volatile("s_waitcnt lgkmcnt(0)" ::: "memory"); \
    __builtin_amdgcn_sched_barrier(0); \
    __builtin_amdgcn_s_setprio(1); } while (0)
#define PH_BOT() do { __builtin_amdgcn_s_setprio(0); \
    __builtin_amdgcn_sched_barrier(0); \
    __builtin_amdgcn_s_barrier(); } while (0)
#define PH_BOT_VM(n) do { __builtin_amdgcn_s_setprio(0); \
    __builtin_amdgcn_sched_barrier(0); \
    asm volatile("s_waitcnt vmcnt(" #n ")" ::: "memory"); \
    __builtin_amdgcn_sched_barrier(0); \
    __builtin_amdgcn_s_barrier(); } while (0)

  // prologue: tile0 (B,A) + B(1); wait tile0 landed, keep B(1) (4 loads) in flight
  STG_B(0, 0); STG_B(0, 1); STG_A(0, 0); STG_A(0, 1); STG_B(1, 0); STG_B(1, 1);
  asm volatile("s_waitcnt vmcnt(4)" ::: "memory");
  __builtin_amdgcn_sched_barrier(0);
  __builtin_amdgcn_s_barrier();

  for (int t = 0; t < 5; ++t) {
    const int k0 = 2 * t;
    // ph1
    DS_B(0); DS_A(0, 0); STG_A(k0 + 1, 0); STG_A(k0 + 1, 1);
    PH_TOP(); MFMA_Q(0); PH_BOT();
    // ph2
    DS_A(0, 1); STG_B(k0 + 2, 0);
    PH_TOP(); MFMA_Q(1); PH_BOT();
    // ph3
    DS_A(0, 2); STG_B(k0 + 2, 1);
    PH_TOP(); MFMA_Q(2); PH_BOT();
    // ph4
    DS_A(0, 3);
    PH_TOP(); MFMA_Q(3); PH_BOT_VM(4);
    // ph5
    DS_B(1); DS_A(1, 0); STG_A(k0 + 2, 0);
    PH_TOP(); MFMA_Q(0); PH_BOT();
    // ph6
    DS_A(1, 1); STG_A(k0 + 2, 1);
    PH_TOP(); MFMA_Q(1); PH_BOT();
    // ph7
    DS_A(1, 2); STG_B(k0 + 3, 0);
    PH_TOP(); MFMA_Q(2); PH_BOT();
    // ph8
    DS_A(1, 3); STG_B(k0 + 3, 1);
    PH_TOP(); MFMA_Q(3); PH_BOT_VM(4);
  }

  // final iteration t=5 (tiles 10, 11): only A(11) left to stage
  DS_B(0); DS_A(0, 0); STG_A(11, 0); STG_A(11, 1);
  PH_TOP(); MFMA_Q(0); PH_BOT();
  DS_A(0, 1);
  PH_TOP(); MFMA_Q(1); PH_BOT();
  DS_A(0, 2);
  PH_TOP(); MFMA_Q(2); PH_BOT();
  DS_A(0, 3);
  PH_TOP(); MFMA_Q(3); PH_BOT_VM(0);
  DS_B(1); DS_A(1, 0);
  PH_TOP(); MFMA_Q(0); PH_BOT();
  DS_A(1, 1);
  PH_TOP(); MFMA_Q(1); PH_BOT();
  DS_A(1, 2);
  PH_TOP(); MFMA_Q(2); PH_BOT();
  DS_A(1, 3);
  PH_TOP(); MFMA_Q(3); PH_BOT();

  // ---------------- epilogue: row-wise (max, sumexp) over this block's 256 cols ----------------
  float* cm = reinterpret_cast<float*>(As);   // [4][BM] wn-major scratch
  float* cl = reinterpret_cast<float*>(Bs);
#pragma unroll
  for (int mt = 0; mt < 8; ++mt)
#pragma unroll
    for (int r = 0; r < 4; ++r) {
      float v0 = acc[mt][0][r], v1 = acc[mt][1][r], v2 = acc[mt][2][r], v3 = acc[mt][3][r];
      float m = fmaxf(fmaxf(v0, v1), fmaxf(v2, v3));
      float l = __expf(v0 - m) + __expf(v1 - m) + __expf(v2 - m) + __expf(v3 - m);
#pragma unroll
      for (int mask = 1; mask < 16; mask <<= 1) {   // combine 16 col-subsets (same row)
        float om = __shfl_xor(m, mask, 64);
        float ol = __shfl_xor(l, mask, 64);
        float mn = fmaxf(m, om);
        l = l * __expf(m - mn) + ol * __expf(om - mn);
        m = mn;
      }
      if (l15 == 0) {
        int rl = wm * 128 + mt * 16 + l4 * 4 + r;
        cm[wn * BM + rl] = m;
        cl[wn * BM + rl] = l;
      }
    }
  __syncthreads();
  if (tid < BM) {
    float m0 = cm[tid],          l0 = cl[tid];
    float m1 = cm[BM + tid],     l1 = cl[BM + tid];
    float m2 = cm[2 * BM + tid], l2 = cl[2 * BM + tid];
    float m3 = cm[3 * BM + tid], l3 = cl[3 * BM + tid];
    float mn = fmaxf(fmaxf(m0, m1), fmaxf(m2, m3));
    float ll = l0 * __expf(m0 - mn) + l1 * __expf(m1 - mn) +
               l2 * __expf(m2 - mn) + l3 * __expf(m3 - mn);
    size_t g = (size_t)(rb * BM + tid) * NPART + cb;
    pm[g] = mn;
    pl[g] = ll;
  }

#undef STG_A
#undef STG_B
#undef DS_A
#undef DS_B
#undef MFMA_Q
#undef PH_TOP
#undef PH_BOT
#undef PH_BOT_VM
}

// ---------------- loss stage 1: 128 blocks x 64 rows, partial sums ----------------
__global__ void loss_stage1_kernel(const float* __restrict__ pm, const float* __restrict__ pl,
                                   const float* __restrict__ dg, float* __restrict__ partial) {
  const int tid = threadIdx.x;        // 64 threads, one row each
  const int r   = blockIdx.x * L1R + tid;

  const float4* pmr = reinterpret_cast<const float4*>(pm + (size_t)r * NPART);
  const float4* plr = reinterpret_cast<const float4*>(pl + (size_t)r * NPART);

  float m = -1e30f, l = 0.f;
#pragma unroll
  for (int q = 0; q < NPART / 4; ++q) {
    float4 mv = pmr[q];
    float4 lv = plr[q];
#pragma unroll
    for (int k = 0; k < 4; ++k) {
      float m2 = (&mv.x)[k], l2 = (&lv.x)[k];
      float mn = fmaxf(m, m2);
      l = l * __expf(m - mn) + l2 * __expf(m2 - mn);
      m = mn;
    }
  }
  float local = m + __logf(l) - dg[r];

#pragma unroll
  for (int off = 32; off; off >>= 1) local += __shfl_xor(local, off, 64);
  if (tid == 0) partial[blockIdx.x] = local;
}

// ---------------- loss stage 2: reduce 128 partials -> loss ----------------
__global__ void loss_stage2_kernel(const float* __restrict__ partial, float* __restrict__ out) {
  const int tid = threadIdx.x;        // 128 threads
  float v = partial[tid];
#pragma unroll
  for (int off = 32; off; off >>= 1) v += __shfl_xor(v, off, 64);
  __shared__ float red[2];
  if ((tid & 63) == 0) red[tid >> 6] = v;
  __syncthreads();
  if (tid == 0) out[0] = (red[0] + red[1]) / (float)BS;
}

extern "C" void kernel_launch(void* const* d_in, const int* in_sizes, int n_in,
                              void* d_out, int out_size, void* d_ws, size_t ws_size,
                              hipStream_t stream) {
  const float* nl = (const float*)d_in[0];
  const float* cd = (const float*)d_in[1];
  float* out = (float*)d_out;

  const size_t NEL = (size_t)BS * DIM;

  unsigned short* nlb = (unsigned short*)d_ws;       // NEL bf16
  unsigned short* cdb = nlb + NEL;                   // NEL bf16
  float* pm = (float*)(cdb + NEL);                   // BS*NPART
  float* pl = pm + (size_t)BS * NPART;               // BS*NPART
  float* dg = pl + (size_t)BS * NPART;               // BS
  float* partial = dg + BS;                          // L1B

  // out = [loss, code_vec copy, nl_vec copy]
  prep_kernel<<<BS / 4, 256, 0, stream>>>(nl, cd, out + 1, out + 1 + NEL, nlb, cdb, dg);
  gemm_lse_kernel<<<dim3(NPART, BS / BM), 512, 0, stream>>>(nlb, cdb, pm, pl);
  loss_stage1_kernel<<<L1B, 64, 0, stream>>>(pm, pl, dg, partial);
  loss_stage2_kernel<<<1, 128, 0, stream>>>(partial, out);
}

// Round 2
// 229.408 us; speedup vs baseline: 1.0962x; 1.0962x over previous
//
#include <hip/hip_runtime.h>

#define BS     8192
#define DIM    768
#define NPART  32               // BS / BN column partitions
#define BM     256
#define BN     256
#define BK     64
#define NKT    (DIM / BK)       // 12 k-tiles
#define L1B    128              // loss stage-1 blocks
#define L1R    (BS / L1B)       // rows per stage-1 block (64)

typedef __bf16 bfrag_t __attribute__((ext_vector_type(8)));
typedef float  facc_t  __attribute__((ext_vector_type(4)));
typedef float  f4raw   __attribute__((ext_vector_type(4)));

typedef const __attribute__((address_space(1))) void gv_t;
typedef __attribute__((address_space(3))) void lv_t;

__device__ __forceinline__ void gll16(const void* g, void* l) {
  // async global->LDS DMA, 16B/lane; LDS dest = wave-uniform base + lane*16
  __builtin_amdgcn_global_load_lds((gv_t*)g, (lv_t*)l, 16, 0, 0);
}

__device__ __forceinline__ unsigned short f2bf(float f) {
  union { float f; unsigned u; } v; v.f = f;
  unsigned u = v.u;
  return (unsigned short)((u + 0x7FFFu + ((u >> 16) & 1u)) >> 16);  // RNE
}

// ---------------- fused: fp32 copy-out (both), bf16 convert (both), diag ----------------
__global__ void prep_kernel(const float* __restrict__ nl, const float* __restrict__ cd,
                            float* __restrict__ cd_copy, float* __restrict__ nl_copy,
                            unsigned short* __restrict__ nlb, unsigned short* __restrict__ cdb,
                            float* __restrict__ dg) {
  const int lane = threadIdx.x & 63;
  const int wave = threadIdx.x >> 6;
  const int row  = blockIdx.x * 4 + wave;
  const size_t rbase = (size_t)row * DIM;
  const float4* ar = reinterpret_cast<const float4*>(nl + rbase);
  const float4* br = reinterpret_cast<const float4*>(cd + rbase);
  float4* wa = reinterpret_cast<float4*>(nl_copy + rbase);
  float4* wb = reinterpret_cast<float4*>(cd_copy + rbase);
  ushort4* ba = reinterpret_cast<ushort4*>(nlb + rbase);
  ushort4* bb = reinterpret_cast<ushort4*>(cdb + rbase);

  float s = 0.f;
#pragma unroll
  for (int i = 0; i < 3; ++i) {                 // 192 float4 per row, 3 per lane
    int idx = lane + 64 * i;
    float4 x = ar[idx];
    float4 y = br[idx];
    wa[idx] = x;
    wb[idx] = y;
    ushort4 xb, yb;
    xb.x = f2bf(x.x); xb.y = f2bf(x.y); xb.z = f2bf(x.z); xb.w = f2bf(x.w);
    yb.x = f2bf(y.x); yb.y = f2bf(y.y); yb.z = f2bf(y.z); yb.w = f2bf(y.w);
    ba[idx] = xb;
    bb[idx] = yb;
    s += x.x * y.x + x.y * y.y + x.z * y.z + x.w * y.w;
  }
#pragma unroll
  for (int off = 32; off; off >>= 1) s += __shfl_xor(s, off, 64);
  if (lane == 0) dg[row] = s;
}

// ---------------- 256x256 8-phase pipelined GEMM (bf16 MFMA) + lse partials ----------------
// Identical schedule to R1, except fragment loads are inline-asm ds_read_b128
// (invisible to the compiler's waitcnt pass, so it cannot insert per-phase
// vmcnt drains against the in-flight global_load_lds LDS writes).
__global__ __launch_bounds__(512, 2) void gemm_lse_kernel(
    const unsigned short* __restrict__ Abf,
    const unsigned short* __restrict__ Bbf,
    float* __restrict__ pm, float* __restrict__ pl) {
  __shared__ __align__(16) unsigned short As[2 * BM * BK];   // 64 KB
  __shared__ __align__(16) unsigned short Bs[2 * BN * BK];   // 64 KB

  const int tid  = threadIdx.x;
  const int lane = tid & 63;
  const int wave = tid >> 6;
  const int wm   = wave >> 2;      // 0..1  M half
  const int wn   = wave & 3;       // 0..3  N quarter
  const int l15  = lane & 15;
  const int l4   = lane >> 4;
  const int swz  = l15 & 7;
  const int cb   = blockIdx.x;
  const int rb   = blockIdx.y;

  // 32-bit LDS byte addresses for asm ds_read (gfx9+: low 32b of flat shared ptr = LDS offset)
  const unsigned lasb = (unsigned)(uintptr_t)(void*)&As[0];
  const unsigned lbsb = (unsigned)(uintptr_t)(void*)&Bs[0];
  // k-slice byte offsets within a row (XOR-swizzled), ks=0 and ks=1
  const unsigned kb0 = (unsigned)(((0 * 4 + l4) ^ swz) * 16);
  const unsigned kb1 = (unsigned)(((1 * 4 + l4) ^ swz) * 16);
  const unsigned a0 = lasb + (unsigned)(wm * 128 + l15) * 128 + kb0;
  const unsigned a1 = lasb + (unsigned)(wm * 128 + l15) * 128 + kb1;
  const unsigned b0 = lbsb + (unsigned)(wn * 64 + l15) * 128 + kb0;
  const unsigned b1 = lbsb + (unsigned)(wn * 64 + l15) * 128 + kb1;

  // staging: unit u (16B) of a tile holds global (row=u>>3, c8=(u&7)^(row&7))
  size_t aoff[4], boff[4];
  int ldso[4];
#pragma unroll
  for (int p = 0; p < 4; ++p) {
    int u   = p * 512 + tid;
    int row = u >> 3;
    int c8  = (u & 7) ^ (row & 7);
    aoff[p] = (size_t)(rb * BM + row) * DIM + c8 * 8;
    boff[p] = (size_t)(cb * BN + row) * DIM + c8 * 8;
    ldso[p] = u * 8;               // shorts within one buf
  }

#define STG_A(kt, h) do { \
    gll16(Abf + aoff[2*(h)]   + (size_t)(kt) * BK, &As[(((kt) & 1) << 14) + ldso[2*(h)]]); \
    gll16(Abf + aoff[2*(h)+1] + (size_t)(kt) * BK, &As[(((kt) & 1) << 14) + ldso[2*(h)+1]]); \
  } while (0)
#define STG_B(kt, h) do { \
    gll16(Bbf + boff[2*(h)]   + (size_t)(kt) * BK, &Bs[(((kt) & 1) << 14) + ldso[2*(h)]]); \
    gll16(Bbf + boff[2*(h)+1] + (size_t)(kt) * BK, &Bs[(((kt) & 1) << 14) + ldso[2*(h)+1]]); \
  } while (0)

  f4raw af[2][2];   // 2 m-tiles x 2 ks, reloaded each phase (asm ds_read outputs)
  f4raw bf[4][2];   // 4 n-tiles x 2 ks, loaded at ph1/ph5, live across the K-tile
  facc_t acc[8][4];
#pragma unroll
  for (int mt = 0; mt < 8; ++mt)
#pragma unroll
    for (int nt = 0; nt < 4; ++nt) acc[mt][nt] = (facc_t){0.f, 0.f, 0.f, 0.f};

#define DSR(dst, addr, off) \
  asm volatile("ds_read_b128 %0, %1 offset:%2" : "=v"(dst) : "v"(addr), "n"(off))

#define DS_A(b, q) do { \
    DSR(af[0][0], a0, (b) * 32768 + (2*(q)+0) * 2048); \
    DSR(af[0][1], a1, (b) * 32768 + (2*(q)+0) * 2048); \
    DSR(af[1][0], a0, (b) * 32768 + (2*(q)+1) * 2048); \
    DSR(af[1][1], a1, (b) * 32768 + (2*(q)+1) * 2048); \
  } while (0)
#define DS_B(b) do { \
    DSR(bf[0][0], b0, (b) * 32768 + 0 * 2048); \
    DSR(bf[0][1], b1, (b) * 32768 + 0 * 2048); \
    DSR(bf[1][0], b0, (b) * 32768 + 1 * 2048); \
    DSR(bf[1][1], b1, (b) * 32768 + 1 * 2048); \
    DSR(bf[2][0], b0, (b) * 32768 + 2 * 2048); \
    DSR(bf[2][1], b1, (b) * 32768 + 2 * 2048); \
    DSR(bf[3][0], b0, (b) * 32768 + 3 * 2048); \
    DSR(bf[3][1], b1, (b) * 32768 + 3 * 2048); \
  } while (0)
#define MFMA_Q(q) do { \
    _Pragma("unroll") \
    for (int i_ = 0; i_ < 2; ++i_) \
      _Pragma("unroll") \
      for (int n_ = 0; n_ < 4; ++n_) { \
        acc[2*(q)+i_][n_] = __builtin_amdgcn_mfma_f32_16x16x32_bf16( \
            __builtin_bit_cast(bfrag_t, af[i_][0]), __builtin_bit_cast(bfrag_t, bf[n_][0]), \
            acc[2*(q)+i_][n_], 0, 0, 0); \
        acc[2*(q)+i_][n_] = __builtin_amdgcn_mfma_f32_16x16x32_bf16( \
            __builtin_bit_cast(bfrag_t, af[i_][1]), __builtin_bit_cast(bfrag_t, bf[n_][1]), \
            acc[2*(q)+i_][n_], 0, 0, 0); \
      } } while (0)

#define PH_TOP() do { __builtin_amdgcn_s_barrier(); \
    asm volatile("s_waitcnt lgkmcnt(0)" ::: "memory"); \
    __builtin_amdgcn_sched_barrier(0); \
    __builtin_amdgcn_s_setprio(1); } while (0)
#define PH_BOT() do { __builtin_amdgcn_s_setprio(0); \
    __builtin_amdgcn_sched_barrier(0); \
    __builtin_amdgcn_s_barrier(); } while (0)
#define PH_BOT_VM(n) do { __builtin_amdgcn_s_setprio(0); \
    __builtin_amdgcn_sched_barrier(0); \
    asm volatile("s_waitcnt vmcnt(" #n ")" ::: "memory"); \
    __builtin_amdgcn_sched_barrier(0); \
    __builtin_amdgcn_s_barrier(); } while (0)

  // prologue: tile0 (B,A) + B(1); wait tile0 landed, keep B(1) (4 loads) in flight
  STG_B(0, 0); STG_B(0, 1); STG_A(0, 0); STG_A(0, 1); STG_B(1, 0); STG_B(1, 1);
  asm volatile("s_waitcnt vmcnt(4)" ::: "memory");
  __builtin_amdgcn_sched_barrier(0);
  __builtin_amdgcn_s_barrier();

  for (int t = 0; t < 5; ++t) {
    const int k0 = 2 * t;
    // ph1
    DS_B(0); DS_A(0, 0); STG_A(k0 + 1, 0); STG_A(k0 + 1, 1);
    PH_TOP(); MFMA_Q(0); PH_BOT();
    // ph2
    DS_A(0, 1); STG_B(k0 + 2, 0);
    PH_TOP(); MFMA_Q(1); PH_BOT();
    // ph3
    DS_A(0, 2); STG_B(k0 + 2, 1);
    PH_TOP(); MFMA_Q(2); PH_BOT();
    // ph4
    DS_A(0, 3);
    PH_TOP(); MFMA_Q(3); PH_BOT_VM(4);
    // ph5
    DS_B(1); DS_A(1, 0); STG_A(k0 + 2, 0);
    PH_TOP(); MFMA_Q(0); PH_BOT();
    // ph6
    DS_A(1, 1); STG_A(k0 + 2, 1);
    PH_TOP(); MFMA_Q(1); PH_BOT();
    // ph7
    DS_A(1, 2); STG_B(k0 + 3, 0);
    PH_TOP(); MFMA_Q(2); PH_BOT();
    // ph8
    DS_A(1, 3); STG_B(k0 + 3, 1);
    PH_TOP(); MFMA_Q(3); PH_BOT_VM(4);
  }

  // final iteration t=5 (tiles 10, 11): only A(11) left to stage
  DS_B(0); DS_A(0, 0); STG_A(11, 0); STG_A(11, 1);
  PH_TOP(); MFMA_Q(0); PH_BOT();
  DS_A(0, 1);
  PH_TOP(); MFMA_Q(1); PH_BOT();
  DS_A(0, 2);
  PH_TOP(); MFMA_Q(2); PH_BOT();
  DS_A(0, 3);
  PH_TOP(); MFMA_Q(3); PH_BOT_VM(0);
  DS_B(1); DS_A(1, 0);
  PH_TOP(); MFMA_Q(0); PH_BOT();
  DS_A(1, 1);
  PH_TOP(); MFMA_Q(1); PH_BOT();
  DS_A(1, 2);
  PH_TOP(); MFMA_Q(2); PH_BOT();
  DS_A(1, 3);
  PH_TOP(); MFMA_Q(3); PH_BOT();

  // ---------------- epilogue: row-wise (max, sumexp) over this block's 256 cols ----------------
  float* cm = reinterpret_cast<float*>(As);   // [4][BM] wn-major scratch
  float* cl = reinterpret_cast<float*>(Bs);
#pragma unroll
  for (int mt = 0; mt < 8; ++mt)
#pragma unroll
    for (int r = 0; r < 4; ++r) {
      float v0 = acc[mt][0][r], v1 = acc[mt][1][r], v2 = acc[mt][2][r], v3 = acc[mt][3][r];
      float m = fmaxf(fmaxf(v0, v1), fmaxf(v2, v3));
      float l = __expf(v0 - m) + __expf(v1 - m) + __expf(v2 - m) + __expf(v3 - m);
#pragma unroll
      for (int mask = 1; mask < 16; mask <<= 1) {   // combine 16 col-subsets (same row)
        float om = __shfl_xor(m, mask, 64);
        float ol = __shfl_xor(l, mask, 64);
        float mn = fmaxf(m, om);
        l = l * __expf(m - mn) + ol * __expf(om - mn);
        m = mn;
      }
      if (l15 == 0) {
        int rl = wm * 128 + mt * 16 + l4 * 4 + r;
        cm[wn * BM + rl] = m;
        cl[wn * BM + rl] = l;
      }
    }
  __syncthreads();
  if (tid < BM) {
    float m0 = cm[tid],          l0 = cl[tid];
    float m1 = cm[BM + tid],     l1 = cl[BM + tid];
    float m2 = cm[2 * BM + tid], l2 = cl[2 * BM + tid];
    float m3 = cm[3 * BM + tid], l3 = cl[3 * BM + tid];
    float mn = fmaxf(fmaxf(m0, m1), fmaxf(m2, m3));
    float ll = l0 * __expf(m0 - mn) + l1 * __expf(m1 - mn) +
               l2 * __expf(m2 - mn) + l3 * __expf(m3 - mn);
    size_t g = (size_t)(rb * BM + tid) * NPART + cb;
    pm[g] = mn;
    pl[g] = ll;
  }

#undef STG_A
#undef STG_B
#undef DSR
#undef DS_A
#undef DS_B
#undef MFMA_Q
#undef PH_TOP
#undef PH_BOT
#undef PH_BOT_VM
}

// ---------------- loss stage 1: 128 blocks x 64 rows, partial sums ----------------
__global__ void loss_stage1_kernel(const float* __restrict__ pm, const float* __restrict__ pl,
                                   const float* __restrict__ dg, float* __restrict__ partial) {
  const int tid = threadIdx.x;        // 64 threads, one row each
  const int r   = blockIdx.x * L1R + tid;

  const float4* pmr = reinterpret_cast<const float4*>(pm + (size_t)r * NPART);
  const float4* plr = reinterpret_cast<const float4*>(pl + (size_t)r * NPART);

  float m = -1e30f, l = 0.f;
#pragma unroll
  for (int q = 0; q < NPART / 4; ++q) {
    float4 mv = pmr[q];
    float4 lv = plr[q];
#pragma unroll
    for (int k = 0; k < 4; ++k) {
      float m2 = (&mv.x)[k], l2 = (&lv.x)[k];
      float mn = fmaxf(m, m2);
      l = l * __expf(m - mn) + l2 * __expf(m2 - mn);
      m = mn;
    }
  }
  float local = m + __logf(l) - dg[r];

#pragma unroll
  for (int off = 32; off; off >>= 1) local += __shfl_xor(local, off, 64);
  if (tid == 0) partial[blockIdx.x] = local;
}

// ---------------- loss stage 2: reduce 128 partials -> loss ----------------
__global__ void loss_stage2_kernel(const float* __restrict__ partial, float* __restrict__ out) {
  const int tid = threadIdx.x;        // 128 threads
  float v = partial[tid];
#pragma unroll
  for (int off = 32; off; off >>= 1) v += __shfl_xor(v, off, 64);
  __shared__ float red[2];
  if ((tid & 63) == 0) red[tid >> 6] = v;
  __syncthreads();
  if (tid == 0) out[0] = (red[0] + red[1]) / (float)BS;
}

extern "C" void kernel_launch(void* const* d_in, const int* in_sizes, int n_in,
                              void* d_out, int out_size, void* d_ws, size_t ws_size,
                              hipStream_t stream) {
  const float* nl = (const float*)d_in[0];
  const float* cd = (const float*)d_in[1];
  float* out = (float*)d_out;

  const size_t NEL = (size_t)BS * DIM;

  unsigned short* nlb = (unsigned short*)d_ws;       // NEL bf16
  unsigned short* cdb = nlb + NEL;                   // NEL bf16
  float* pm = (float*)(cdb + NEL);                   // BS*NPART
  float* pl = pm + (size_t)BS * NPART;               // BS*NPART
  float* dg = pl + (size_t)BS * NPART;               // BS
  float* partial = dg + BS;                          // L1B

  // out = [loss, code_vec copy, nl_vec copy]
  prep_kernel<<<BS / 4, 256, 0, stream>>>(nl, cd, out + 1, out + 1 + NEL, nlb, cdb, dg);
  gemm_lse_kernel<<<dim3(NPART, BS / BM), 512, 0, stream>>>(nlb, cdb, pm, pl);
  loss_stage1_kernel<<<L1B, 64, 0, stream>>>(pm, pl, dg, partial);
  loss_stage2_kernel<<<1, 128, 0, stream>>>(partial, out);
}

// Round 3
// 227.023 us; speedup vs baseline: 1.1077x; 1.0105x over previous
//
#include <hip/hip_runtime.h>

#define BS     8192
#define DIM    768
#define NPART  32               // BS / BN column partitions
#define BM     256
#define BN     256
#define BK     64
#define NKT    (DIM / BK)       // 12 k-tiles
#define L1B    128              // loss stage-1 blocks
#define L1R    (BS / L1B)       // rows per stage-1 block (64)

typedef __bf16 bfrag_t __attribute__((ext_vector_type(8)));
typedef float  facc_t  __attribute__((ext_vector_type(4)));
typedef float  f4raw   __attribute__((ext_vector_type(4)));

typedef const __attribute__((address_space(1))) void gv_t;
typedef __attribute__((address_space(3))) void lv_t;

__device__ __forceinline__ void gll16(const void* g, void* l) {
  // async global->LDS DMA, 16B/lane; LDS dest = wave-uniform base + lane*16
  __builtin_amdgcn_global_load_lds((gv_t*)g, (lv_t*)l, 16, 0, 0);
}

__device__ __forceinline__ unsigned short f2bf(float f) {
  union { float f; unsigned u; } v; v.f = f;
  unsigned u = v.u;
  return (unsigned short)((u + 0x7FFFu + ((u >> 16) & 1u)) >> 16);  // RNE
}

// ---------------- fused: fp32 copy-out (both), bf16 convert (both), diag ----------------
__global__ void prep_kernel(const float* __restrict__ nl, const float* __restrict__ cd,
                            float* __restrict__ cd_copy, float* __restrict__ nl_copy,
                            unsigned short* __restrict__ nlb, unsigned short* __restrict__ cdb,
                            float* __restrict__ dg) {
  const int lane = threadIdx.x & 63;
  const int wave = threadIdx.x >> 6;
  const int row  = blockIdx.x * 4 + wave;
  const size_t rbase = (size_t)row * DIM;
  const float4* ar = reinterpret_cast<const float4*>(nl + rbase);
  const float4* br = reinterpret_cast<const float4*>(cd + rbase);
  float4* wa = reinterpret_cast<float4*>(nl_copy + rbase);
  float4* wb = reinterpret_cast<float4*>(cd_copy + rbase);
  ushort4* ba = reinterpret_cast<ushort4*>(nlb + rbase);
  ushort4* bb = reinterpret_cast<ushort4*>(cdb + rbase);

  float s = 0.f;
#pragma unroll
  for (int i = 0; i < 3; ++i) {                 // 192 float4 per row, 3 per lane
    int idx = lane + 64 * i;
    float4 x = ar[idx];
    float4 y = br[idx];
    wa[idx] = x;
    wb[idx] = y;
    ushort4 xb, yb;
    xb.x = f2bf(x.x); xb.y = f2bf(x.y); xb.z = f2bf(x.z); xb.w = f2bf(x.w);
    yb.x = f2bf(y.x); yb.y = f2bf(y.y); yb.z = f2bf(y.z); yb.w = f2bf(y.w);
    ba[idx] = xb;
    bb[idx] = yb;
    s += x.x * y.x + x.y * y.y + x.z * y.z + x.w * y.w;
  }
#pragma unroll
  for (int off = 32; off; off >>= 1) s += __shfl_xor(s, off, 64);
  if (lane == 0) dg[row] = s;
}

// ---------------- 256x256 8-phase pipelined GEMM (bf16 MFMA) + lse partials ----------------
// Identical to R2 except: waitcnt inline-asms carry NO "memory" clobber (a memory
// clobber makes the asm mayLoad/mayStore, so SIInsertWaitcnts inserts vmcnt(0)
// before it each phase, draining the staging pipeline). Ordering is maintained by
// volatile-asm program order + sched_barrier(0) fences (rule 18).
__global__ __launch_bounds__(512, 2) void gemm_lse_kernel(
    const unsigned short* __restrict__ Abf,
    const unsigned short* __restrict__ Bbf,
    float* __restrict__ pm, float* __restrict__ pl) {
  __shared__ __align__(16) unsigned short As[2 * BM * BK];   // 64 KB
  __shared__ __align__(16) unsigned short Bs[2 * BN * BK];   // 64 KB

  const int tid  = threadIdx.x;
  const int lane = tid & 63;
  const int wave = tid >> 6;
  const int wm   = wave >> 2;      // 0..1  M half
  const int wn   = wave & 3;       // 0..3  N quarter
  const int l15  = lane & 15;
  const int l4   = lane >> 4;
  const int swz  = l15 & 7;
  const int cb   = blockIdx.x;
  const int rb   = blockIdx.y;

  // 32-bit LDS byte addresses for asm ds_read (low 32b of flat shared ptr = LDS offset)
  const unsigned lasb = (unsigned)(uintptr_t)(void*)&As[0];
  const unsigned lbsb = (unsigned)(uintptr_t)(void*)&Bs[0];
  // k-slice byte offsets within a row (XOR-swizzled), ks=0 and ks=1
  const unsigned kb0 = (unsigned)(((0 * 4 + l4) ^ swz) * 16);
  const unsigned kb1 = (unsigned)(((1 * 4 + l4) ^ swz) * 16);
  const unsigned a0 = lasb + (unsigned)(wm * 128 + l15) * 128 + kb0;
  const unsigned a1 = lasb + (unsigned)(wm * 128 + l15) * 128 + kb1;
  const unsigned b0 = lbsb + (unsigned)(wn * 64 + l15) * 128 + kb0;
  const unsigned b1 = lbsb + (unsigned)(wn * 64 + l15) * 128 + kb1;

  // staging: unit u (16B) of a tile holds global (row=u>>3, c8=(u&7)^(row&7))
  size_t aoff[4], boff[4];
  int ldso[4];
#pragma unroll
  for (int p = 0; p < 4; ++p) {
    int u   = p * 512 + tid;
    int row = u >> 3;
    int c8  = (u & 7) ^ (row & 7);
    aoff[p] = (size_t)(rb * BM + row) * DIM + c8 * 8;
    boff[p] = (size_t)(cb * BN + row) * DIM + c8 * 8;
    ldso[p] = u * 8;               // shorts within one buf
  }

#define STG_A(kt, h) do { \
    gll16(Abf + aoff[2*(h)]   + (size_t)(kt) * BK, &As[(((kt) & 1) << 14) + ldso[2*(h)]]); \
    gll16(Abf + aoff[2*(h)+1] + (size_t)(kt) * BK, &As[(((kt) & 1) << 14) + ldso[2*(h)+1]]); \
  } while (0)
#define STG_B(kt, h) do { \
    gll16(Bbf + boff[2*(h)]   + (size_t)(kt) * BK, &Bs[(((kt) & 1) << 14) + ldso[2*(h)]]); \
    gll16(Bbf + boff[2*(h)+1] + (size_t)(kt) * BK, &Bs[(((kt) & 1) << 14) + ldso[2*(h)+1]]); \
  } while (0)

  f4raw af[2][2];   // 2 m-tiles x 2 ks, reloaded each phase (asm ds_read outputs)
  f4raw bf[4][2];   // 4 n-tiles x 2 ks, loaded at ph1/ph5, live across the K-tile
  facc_t acc[8][4];
#pragma unroll
  for (int mt = 0; mt < 8; ++mt)
#pragma unroll
    for (int nt = 0; nt < 4; ++nt) acc[mt][nt] = (facc_t){0.f, 0.f, 0.f, 0.f};

#define DSR(dst, addr, off) \
  asm volatile("ds_read_b128 %0, %1 offset:%2" : "=v"(dst) : "v"(addr), "n"(off))

#define DS_A(b, q) do { \
    DSR(af[0][0], a0, (b) * 32768 + (2*(q)+0) * 2048); \
    DSR(af[0][1], a1, (b) * 32768 + (2*(q)+0) * 2048); \
    DSR(af[1][0], a0, (b) * 32768 + (2*(q)+1) * 2048); \
    DSR(af[1][1], a1, (b) * 32768 + (2*(q)+1) * 2048); \
  } while (0)
#define DS_B(b) do { \
    DSR(bf[0][0], b0, (b) * 32768 + 0 * 2048); \
    DSR(bf[0][1], b1, (b) * 32768 + 0 * 2048); \
    DSR(bf[1][0], b0, (b) * 32768 + 1 * 2048); \
    DSR(bf[1][1], b1, (b) * 32768 + 1 * 2048); \
    DSR(bf[2][0], b0, (b) * 32768 + 2 * 2048); \
    DSR(bf[2][1], b1, (b) * 32768 + 2 * 2048); \
    DSR(bf[3][0], b0, (b) * 32768 + 3 * 2048); \
    DSR(bf[3][1], b1, (b) * 32768 + 3 * 2048); \
  } while (0)
#define MFMA_Q(q) do { \
    _Pragma("unroll") \
    for (int i_ = 0; i_ < 2; ++i_) \
      _Pragma("unroll") \
      for (int n_ = 0; n_ < 4; ++n_) { \
        acc[2*(q)+i_][n_] = __builtin_amdgcn_mfma_f32_16x16x32_bf16( \
            __builtin_bit_cast(bfrag_t, af[i_][0]), __builtin_bit_cast(bfrag_t, bf[n_][0]), \
            acc[2*(q)+i_][n_], 0, 0, 0); \
        acc[2*(q)+i_][n_] = __builtin_amdgcn_mfma_f32_16x16x32_bf16( \
            __builtin_bit_cast(bfrag_t, af[i_][1]), __builtin_bit_cast(bfrag_t, bf[n_][1]), \
            acc[2*(q)+i_][n_], 0, 0, 0); \
      } } while (0)

#define PH_TOP() do { \
    __builtin_amdgcn_sched_barrier(0); \
    __builtin_amdgcn_s_barrier(); \
    asm volatile("s_waitcnt lgkmcnt(0)"); \
    __builtin_amdgcn_sched_barrier(0); \
    __builtin_amdgcn_s_setprio(1); } while (0)
#define PH_BOT() do { __builtin_amdgcn_s_setprio(0); \
    __builtin_amdgcn_sched_barrier(0); \
    __builtin_amdgcn_s_barrier(); } while (0)
#define PH_BOT_VM(n) do { __builtin_amdgcn_s_setprio(0); \
    __builtin_amdgcn_sched_barrier(0); \
    asm volatile("s_waitcnt vmcnt(" #n ")"); \
    __builtin_amdgcn_sched_barrier(0); \
    __builtin_amdgcn_s_barrier(); } while (0)

  // prologue: tile0 (B,A) + B(1); wait tile0 landed, keep B(1) (4 loads) in flight
  STG_B(0, 0); STG_B(0, 1); STG_A(0, 0); STG_A(0, 1); STG_B(1, 0); STG_B(1, 1);
  __builtin_amdgcn_sched_barrier(0);
  asm volatile("s_waitcnt vmcnt(4)");
  __builtin_amdgcn_sched_barrier(0);
  __builtin_amdgcn_s_barrier();

  for (int t = 0; t < 5; ++t) {
    const int k0 = 2 * t;
    // ph1
    DS_B(0); DS_A(0, 0); STG_A(k0 + 1, 0); STG_A(k0 + 1, 1);
    PH_TOP(); MFMA_Q(0); PH_BOT();
    // ph2
    DS_A(0, 1); STG_B(k0 + 2, 0);
    PH_TOP(); MFMA_Q(1); PH_BOT();
    // ph3
    DS_A(0, 2); STG_B(k0 + 2, 1);
    PH_TOP(); MFMA_Q(2); PH_BOT();
    // ph4
    DS_A(0, 3);
    PH_TOP(); MFMA_Q(3); PH_BOT_VM(4);
    // ph5
    DS_B(1); DS_A(1, 0); STG_A(k0 + 2, 0);
    PH_TOP(); MFMA_Q(0); PH_BOT();
    // ph6
    DS_A(1, 1); STG_A(k0 + 2, 1);
    PH_TOP(); MFMA_Q(1); PH_BOT();
    // ph7
    DS_A(1, 2); STG_B(k0 + 3, 0);
    PH_TOP(); MFMA_Q(2); PH_BOT();
    // ph8
    DS_A(1, 3); STG_B(k0 + 3, 1);
    PH_TOP(); MFMA_Q(3); PH_BOT_VM(4);
  }

  // final iteration t=5 (tiles 10, 11): only A(11) left to stage
  DS_B(0); DS_A(0, 0); STG_A(11, 0); STG_A(11, 1);
  PH_TOP(); MFMA_Q(0); PH_BOT();
  DS_A(0, 1);
  PH_TOP(); MFMA_Q(1); PH_BOT();
  DS_A(0, 2);
  PH_TOP(); MFMA_Q(2); PH_BOT();
  DS_A(0, 3);
  PH_TOP(); MFMA_Q(3); PH_BOT_VM(0);
  DS_B(1); DS_A(1, 0);
  PH_TOP(); MFMA_Q(0); PH_BOT();
  DS_A(1, 1);
  PH_TOP(); MFMA_Q(1); PH_BOT();
  DS_A(1, 2);
  PH_TOP(); MFMA_Q(2); PH_BOT();
  DS_A(1, 3);
  PH_TOP(); MFMA_Q(3); PH_BOT();

  // ---------------- epilogue: row-wise (max, sumexp) over this block's 256 cols ----------------
  float* cm = reinterpret_cast<float*>(As);   // [4][BM] wn-major scratch
  float* cl = reinterpret_cast<float*>(Bs);
#pragma unroll
  for (int mt = 0; mt < 8; ++mt)
#pragma unroll
    for (int r = 0; r < 4; ++r) {
      float v0 = acc[mt][0][r], v1 = acc[mt][1][r], v2 = acc[mt][2][r], v3 = acc[mt][3][r];
      float m = fmaxf(fmaxf(v0, v1), fmaxf(v2, v3));
      float l = __expf(v0 - m) + __expf(v1 - m) + __expf(v2 - m) + __expf(v3 - m);
#pragma unroll
      for (int mask = 1; mask < 16; mask <<= 1) {   // combine 16 col-subsets (same row)
        float om = __shfl_xor(m, mask, 64);
        float ol = __shfl_xor(l, mask, 64);
        float mn = fmaxf(m, om);
        l = l * __expf(m - mn) + ol * __expf(om - mn);
        m = mn;
      }
      if (l15 == 0) {
        int rl = wm * 128 + mt * 16 + l4 * 4 + r;
        cm[wn * BM + rl] = m;
        cl[wn * BM + rl] = l;
      }
    }
  __syncthreads();
  if (tid < BM) {
    float m0 = cm[tid],          l0 = cl[tid];
    float m1 = cm[BM + tid],     l1 = cl[BM + tid];
    float m2 = cm[2 * BM + tid], l2 = cl[2 * BM + tid];
    float m3 = cm[3 * BM + tid], l3 = cl[3 * BM + tid];
    float mn = fmaxf(fmaxf(m0, m1), fmaxf(m2, m3));
    float ll = l0 * __expf(m0 - mn) + l1 * __expf(m1 - mn) +
               l2 * __expf(m2 - mn) + l3 * __expf(m3 - mn);
    size_t g = (size_t)(rb * BM + tid) * NPART + cb;
    pm[g] = mn;
    pl[g] = ll;
  }

#undef STG_A
#undef STG_B
#undef DSR
#undef DS_A
#undef DS_B
#undef MFMA_Q
#undef PH_TOP
#undef PH_BOT
#undef PH_BOT_VM
}

// ---------------- loss stage 1: 128 blocks x 64 rows, partial sums ----------------
__global__ void loss_stage1_kernel(const float* __restrict__ pm, const float* __restrict__ pl,
                                   const float* __restrict__ dg, float* __restrict__ partial) {
  const int tid = threadIdx.x;        // 64 threads, one row each
  const int r   = blockIdx.x * L1R + tid;

  const float4* pmr = reinterpret_cast<const float4*>(pm + (size_t)r * NPART);
  const float4* plr = reinterpret_cast<const float4*>(pl + (size_t)r * NPART);

  float m = -1e30f, l = 0.f;
#pragma unroll
  for (int q = 0; q < NPART / 4; ++q) {
    float4 mv = pmr[q];
    float4 lv = plr[q];
#pragma unroll
    for (int k = 0; k < 4; ++k) {
      float m2 = (&mv.x)[k], l2 = (&lv.x)[k];
      float mn = fmaxf(m, m2);
      l = l * __expf(m - mn) + l2 * __expf(m2 - mn);
      m = mn;
    }
  }
  float local = m + __logf(l) - dg[r];

#pragma unroll
  for (int off = 32; off; off >>= 1) local += __shfl_xor(local, off, 64);
  if (tid == 0) partial[blockIdx.x] = local;
}

// ---------------- loss stage 2: reduce 128 partials -> loss ----------------
__global__ void loss_stage2_kernel(const float* __restrict__ partial, float* __restrict__ out) {
  const int tid = threadIdx.x;        // 128 threads
  float v = partial[tid];
#pragma unroll
  for (int off = 32; off; off >>= 1) v += __shfl_xor(v, off, 64);
  __shared__ float red[2];
  if ((tid & 63) == 0) red[tid >> 6] = v;
  __syncthreads();
  if (tid == 0) out[0] = (red[0] + red[1]) / (float)BS;
}

extern "C" void kernel_launch(void* const* d_in, const int* in_sizes, int n_in,
                              void* d_out, int out_size, void* d_ws, size_t ws_size,
                              hipStream_t stream) {
  const float* nl = (const float*)d_in[0];
  const float* cd = (const float*)d_in[1];
  float* out = (float*)d_out;

  const size_t NEL = (size_t)BS * DIM;

  unsigned short* nlb = (unsigned short*)d_ws;       // NEL bf16
  unsigned short* cdb = nlb + NEL;                   // NEL bf16
  float* pm = (float*)(cdb + NEL);                   // BS*NPART
  float* pl = pm + (size_t)BS * NPART;               // BS*NPART
  float* dg = pl + (size_t)BS * NPART;               // BS
  float* partial = dg + BS;                          // L1B

  // out = [loss, code_vec copy, nl_vec copy]
  prep_kernel<<<BS / 4, 256, 0, stream>>>(nl, cd, out + 1, out + 1 + NEL, nlb, cdb, dg);
  gemm_lse_kernel<<<dim3(NPART, BS / BM), 512, 0, stream>>>(nlb, cdb, pm, pl);
  loss_stage1_kernel<<<L1B, 64, 0, stream>>>(pm, pl, dg, partial);
  loss_stage2_kernel<<<1, 128, 0, stream>>>(partial, out);
}